// Round 2
// baseline (177.693 us; speedup 1.0000x reference)
//
#include <hip/hip_runtime.h>

#define TILE 16

// Per-pixel KAN transform: g = silu(x); cubic B-spline bases N0..N3 (premult 1/6,
// zeroed when x outside knot span) and interval index m (clamped).
struct Tfm { float g, n0, n1, n2, n3; int m; };

template <int TMAX>
__device__ __forceinline__ Tfm kan_transform(float x, float g0, float invh) {
    Tfm t;
    t.g = x / (1.0f + __expf(-x));
    float T = (x - g0) * invh;
    float mf = floorf(T);
    bool inb = (T >= 0.0f) && (T < (float)TMAX);
    mf = fminf(fmaxf(mf, 0.0f), (float)(TMAX - 1));
    float w = T - mf;
    float w2 = w * w;
    float w3 = w2 * w;
    float om = 1.0f - w;
    float sc = inb ? (1.0f / 6.0f) : 0.0f;
    t.n0 = om * om * om * sc;
    t.n1 = (3.0f * w3 - 6.0f * w2 + 4.0f) * sc;
    t.n2 = (-3.0f * w3 + 3.0f * w2 + 3.0f * w + 1.0f) * sc;
    t.n3 = w3 * sc;
    t.m = (int)mf;
    return t;
}

__global__ __launch_bounds__(256, 4) void ZS_MKAN_72121090834671_kernel(
    const float* __restrict__ x,
    const float* __restrict__ base_w1, const float* __restrict__ spline_w1,
    const float* __restrict__ scaler1,
    const float* __restrict__ base_w2, const float* __restrict__ spline_w2,
    const float* __restrict__ scaler2,
    const float* __restrict__ conv_w, const float* __restrict__ conv_b,
    const float* __restrict__ base_w6, const float* __restrict__ spline_w6,
    const float* __restrict__ scaler6,
    float* __restrict__ out)
{
    // SoA transform buffer: stage A uses 3*400=1200 entries, stage B 3*324=972.
    __shared__ float Tg[1200], TN0[1200], TN1[1200], TN2[1200], TN3[1200];
    __shared__ int   Tm[1200];
    __shared__ float sy[6 * 324];        // layer1 out, 18x18 per channel
    __shared__ float sbw1[18];           // base_w1 [k*9+s]
    __shared__ float ssw1[2][9][12];     // spline_w1*scaler1, padded +3 each side
    __shared__ float sbw2[18];
    __shared__ float ssw2[2][9][12];
    __shared__ float scw[36];            // conv_w [o*12+c]
    __shared__ float scb[3];
    __shared__ float sw6[14];            // spline_w6*scaler6, padded (8 coefs)
    __shared__ float sb6;

    const int tid = threadIdx.x;
    const int tx0 = blockIdx.x * TILE;
    const int ty0 = blockIdx.y * TILE;
    const int b   = blockIdx.z;

    // ---- weight preload (padded; pre-multiplied by scaler) ----
    for (int i = tid; i < 216; i += 256) {
        int k = i / 108, r = i % 108, s = r / 12, p = r % 12, c = p - 3;
        float v1 = 0.0f, v2 = 0.0f;
        if (c >= 0 && c < 6) {
            v1 = spline_w1[(k * 9 + s) * 6 + c] * scaler1[k * 9 + s];
            v2 = spline_w2[(k * 9 + s) * 6 + c] * scaler2[k * 9 + s];
        }
        ssw1[k][s][p] = v1;
        ssw2[k][s][p] = v2;
    }
    if (tid < 18) { sbw1[tid] = base_w1[tid]; sbw2[tid] = base_w2[tid]; }
    if (tid < 36) scw[tid] = conv_w[tid];
    if (tid < 3)  scb[tid] = conv_b[tid];
    if (tid < 14) {
        int c = tid - 3;
        sw6[tid] = (c >= 0 && c < 8) ? spline_w6[c] * scaler6[0] : 0.0f;
    }
    if (tid == 0) sb6 = base_w6[0];

    // ---- stage A transform: load x tile + halo2, transform per pixel ----
    for (int i = tid; i < 3 * 400; i += 256) {
        int c = i / 400, r = i % 400, ly = r / 20, lx = r % 20;
        int gy = ty0 - 2 + ly, gx = tx0 - 2 + lx;
        float v = 0.0f;
        if (gy >= 0 && gy < 256 && gx >= 0 && gx < 256)
            v = x[((b * 3 + c) * 256 + gy) * 256 + gx];
        Tfm t = kan_transform<9>(v, -3.0f, 1.5f);
        Tg[i] = t.g; TN0[i] = t.n0; TN1[i] = t.n1; TN2[i] = t.n2; TN3[i] = t.n3;
        Tm[i] = t.m;
    }
    __syncthreads();

    // ---- stage A accumulate: layer1 (3ch -> 6ch) on 18x18 region (origin -1) ----
    for (int i = tid; i < 3 * 324; i += 256) {
        int c = i / 324, r = i % 324, ly = r / 18, lx = r % 18;
        float a0 = 0.0f, a1 = 0.0f;
        int base = c * 400 + ly * 20 + lx;
        #pragma unroll
        for (int s = 0; s < 9; ++s) {
            int p = base + (s / 3) * 20 + (s % 3);
            float g = Tg[p], n0 = TN0[p], n1 = TN1[p], n2 = TN2[p], n3 = TN3[p];
            int m = Tm[p];
            a0 += g * sbw1[s]     + n0 * ssw1[0][s][m]     + n1 * ssw1[0][s][m + 1]
                                  + n2 * ssw1[0][s][m + 2] + n3 * ssw1[0][s][m + 3];
            a1 += g * sbw1[9 + s] + n0 * ssw1[1][s][m]     + n1 * ssw1[1][s][m + 1]
                                  + n2 * ssw1[1][s][m + 2] + n3 * ssw1[1][s][m + 3];
        }
        int gy = ty0 - 1 + ly, gx = tx0 - 1 + lx;
        bool inimg = (gy >= 0 && gy < 256 && gx >= 0 && gx < 256);
        sy[(c * 2 + 0) * 324 + r] = inimg ? a0 : 0.0f;  // layer2 sees ZERO pad
        sy[(c * 2 + 1) * 324 + r] = inimg ? a1 : 0.0f;
    }
    __syncthreads();

    // ---- stage B: layer2 (6->12), two chunks of 3 y-channels ----
    const int ly = tid / 16, lx = tid % 16;
    float z[12];
    #pragma unroll
    for (int cc = 0; cc < 2; ++cc) {
        for (int i = tid; i < 972; i += 256) {
            int c0 = i / 324, r = i % 324;
            float yv = sy[(3 * cc + c0) * 324 + r];
            Tfm t = kan_transform<9>(yv, -3.0f, 1.5f);
            Tg[i] = t.g; TN0[i] = t.n0; TN1[i] = t.n1; TN2[i] = t.n2; TN3[i] = t.n3;
            Tm[i] = t.m;
        }
        __syncthreads();
        #pragma unroll
        for (int c0 = 0; c0 < 3; ++c0) {
            int k = 3 * cc + c0;
            float a0 = 0.0f, a1 = 0.0f;
            int base = c0 * 324 + ly * 18 + lx;
            #pragma unroll
            for (int s = 0; s < 9; ++s) {
                int p = base + (s / 3) * 18 + (s % 3);
                float g = Tg[p], n0 = TN0[p], n1 = TN1[p], n2 = TN2[p], n3 = TN3[p];
                int m = Tm[p];
                a0 += g * sbw2[s]     + n0 * ssw2[0][s][m]     + n1 * ssw2[0][s][m + 1]
                                      + n2 * ssw2[0][s][m + 2] + n3 * ssw2[0][s][m + 3];
                a1 += g * sbw2[9 + s] + n0 * ssw2[1][s][m]     + n1 * ssw2[1][s][m + 1]
                                      + n2 * ssw2[1][s][m + 2] + n3 * ssw2[1][s][m + 3];
            }
            z[2 * k]     = a0;
            z[2 * k + 1] = a1;
        }
        __syncthreads();
    }

    // ---- 1x1 conv (12->3) + KAN layer6 (pointwise) + store ----
    const int gy = ty0 + ly, gx = tx0 + lx;
    #pragma unroll
    for (int o = 0; o < 3; ++o) {
        float v = scb[o];
        #pragma unroll
        for (int c = 0; c < 12; ++c) v += scw[o * 12 + c] * z[c];
        Tfm t = kan_transform<11>(v, -2.2f, 2.5f);
        float sp = t.n0 * sw6[t.m]     + t.n1 * sw6[t.m + 1]
                 + t.n2 * sw6[t.m + 2] + t.n3 * sw6[t.m + 3];
        out[((b * 3 + o) * 256 + gy) * 256 + gx] = t.g * sb6 + sp;
    }
}

extern "C" void kernel_launch(void* const* d_in, const int* in_sizes, int n_in,
                              void* d_out, int out_size, void* d_ws, size_t ws_size,
                              hipStream_t stream) {
    (void)in_sizes; (void)n_in; (void)d_ws; (void)ws_size; (void)out_size;
    const float* x         = (const float*)d_in[0];
    const float* base_w1   = (const float*)d_in[1];
    const float* spline_w1 = (const float*)d_in[2];
    const float* scaler1   = (const float*)d_in[3];
    const float* base_w2   = (const float*)d_in[4];
    const float* spline_w2 = (const float*)d_in[5];
    const float* scaler2   = (const float*)d_in[6];
    const float* conv_w    = (const float*)d_in[7];
    const float* conv_b    = (const float*)d_in[8];
    const float* base_w6   = (const float*)d_in[9];
    const float* spline_w6 = (const float*)d_in[10];
    const float* scaler6   = (const float*)d_in[11];
    float* out = (float*)d_out;

    dim3 grid(256 / TILE, 256 / TILE, 4);
    dim3 block(256);
    ZS_MKAN_72121090834671_kernel<<<grid, block, 0, stream>>>(
        x, base_w1, spline_w1, scaler1, base_w2, spline_w2, scaler2,
        conv_w, conv_b, base_w6, spline_w6, scaler6, out);
}

// Round 3
// 26.273 us; speedup vs baseline: 6.7634x; 6.7634x over previous
//
#include <hip/hip_runtime.h>

#define TILE 16

// Encode one KAN input value: g = silu(v); U = knot coordinate T=(v-g0)*invh if
// inside the knot span [0,tmax), else -1 (maps to zeroed poly slot 0).
__device__ __forceinline__ float2 kan_enc(float v, float g0, float invh, float tmax) {
    float g = v / (1.0f + __expf(-v));
    float T = (v - g0) * invh;
    float U = (T >= 0.0f && T < tmax) ? T : -1.0f;
    float2 r; r.x = g; r.y = U; return r;
}

__device__ __forceinline__ float poly_eval(float4 c, float w) {
    return ((c.w * w + c.z) * w + c.y) * w + c.x;
}

__global__ __launch_bounds__(256) void ZS_MKAN_72121090834671_kernel(
    const float* __restrict__ x,
    const float* __restrict__ base_w1, const float* __restrict__ spline_w1,
    const float* __restrict__ scaler1,
    const float* __restrict__ base_w2, const float* __restrict__ spline_w2,
    const float* __restrict__ scaler2,
    const float* __restrict__ conv_w, const float* __restrict__ conv_b,
    const float* __restrict__ base_w6, const float* __restrict__ spline_w6,
    const float* __restrict__ scaler6,
    float* __restrict__ out)
{
    __shared__ float2 encX[1200];            // x halo transforms: 3ch x 20x20
    __shared__ float2 encY[1944];            // layer1-out transforms: 6ch x 18x18
    __shared__ float4 coefL[2][2][9][10];    // per (layer,k,tap,interval+1) cubic in w
    __shared__ float4 coef6[12];             // layer6: 11 intervals + zero slot
    __shared__ float  sbw[2][18];            // base_w1 / base_w2
    __shared__ float  scw[36], scb[3];       // 1x1 conv
    __shared__ float  sb6;

    const int tid = threadIdx.x;
    const int tx0 = blockIdx.x * TILE;
    const int ty0 = blockIdx.y * TILE;
    const int b   = blockIdx.z;

    // ---- build piecewise-cubic spline tables (W = padded spline_w * scaler) ----
    // value on interval m (w in [0,1)) = c0 + c1 w + c2 w^2 + c3 w^3 with
    // c0=(W0+4W1+W2)/6, c1=3(W2-W0)/6, c2=(3W0-6W1+3W2)/6, c3=(W3-W0+3(W1-W2))/6
    for (int e = tid; e < 360; e += 256) {
        int l = e / 180, r = e % 180, k = r / 90, r2 = r % 90, s = r2 / 10, si = r2 % 10;
        float4 v = make_float4(0.f, 0.f, 0.f, 0.f);
        if (si > 0) {
            const float* sw  = l ? spline_w2 : spline_w1;
            const float* scl = l ? scaler2   : scaler1;
            float sc = scl[k * 9 + s];
            int m = si - 1;
            float W[4];
            #pragma unroll
            for (int j = 0; j < 4; ++j) {
                int c = m - 3 + j;
                W[j] = (c >= 0 && c < 6) ? sw[(k * 9 + s) * 6 + c] * sc : 0.0f;
            }
            const float s6 = 1.0f / 6.0f;
            v.x = (W[0] + 4.0f * W[1] + W[2]) * s6;
            v.y = 3.0f * (W[2] - W[0]) * s6;
            v.z = (3.0f * W[0] - 6.0f * W[1] + 3.0f * W[2]) * s6;
            v.w = (W[3] - W[0] + 3.0f * (W[1] - W[2])) * s6;
        }
        coefL[l][k][s][si] = v;
    }
    if (tid < 12) {
        float4 v = make_float4(0.f, 0.f, 0.f, 0.f);
        if (tid > 0) {
            float sc = scaler6[0];
            int m = tid - 1;
            float W[4];
            #pragma unroll
            for (int j = 0; j < 4; ++j) {
                int c = m - 3 + j;
                W[j] = (c >= 0 && c < 8) ? spline_w6[c] * sc : 0.0f;
            }
            const float s6 = 1.0f / 6.0f;
            v.x = (W[0] + 4.0f * W[1] + W[2]) * s6;
            v.y = 3.0f * (W[2] - W[0]) * s6;
            v.z = (3.0f * W[0] - 6.0f * W[1] + 3.0f * W[2]) * s6;
            v.w = (W[3] - W[0] + 3.0f * (W[1] - W[2])) * s6;
        }
        coef6[tid] = v;
    }
    if (tid < 18) { sbw[0][tid] = base_w1[tid]; sbw[1][tid] = base_w2[tid]; }
    if (tid < 36) scw[tid] = conv_w[tid];
    if (tid < 3)  scb[tid] = conv_b[tid];
    if (tid == 0) sb6 = base_w6[0];

    // ---- encode x tile + halo2 (zero-padded values ARE transformed, per ref) ----
    for (int i = tid; i < 1200; i += 256) {
        int c = i / 400, r = i % 400, ly = r / 20, lx = r % 20;
        int gy = ty0 - 2 + ly, gx = tx0 - 2 + lx;
        float v = 0.0f;
        if ((unsigned)gy < 256u && (unsigned)gx < 256u)
            v = x[((b * 3 + c) * 256 + gy) * 256 + gx];
        encX[i] = kan_enc(v, -3.0f, 1.5f, 9.0f);
    }
    __syncthreads();

    // ---- layer1 (3ch -> 6ch) on 18x18, encode outputs directly ----
    for (int i = tid; i < 972; i += 256) {
        int c = i / 324, r = i % 324, ly = r / 18, lx = r % 18;
        float a0 = 0.0f, a1 = 0.0f;
        int base = c * 400 + ly * 20 + lx;
        #pragma unroll
        for (int s = 0; s < 9; ++s) {
            float2 t = encX[base + (s / 3) * 20 + (s % 3)];
            float mf = floorf(t.y);
            float w  = t.y - mf;
            int  si  = (int)mf + 1;
            a0 += t.x * sbw[0][s]     + poly_eval(coefL[0][0][s][si], w);
            a1 += t.x * sbw[0][9 + s] + poly_eval(coefL[0][1][s][si], w);
        }
        int gy = ty0 - 1 + ly, gx = tx0 - 1 + lx;
        if (!((unsigned)gy < 256u && (unsigned)gx < 256u)) { a0 = 0.0f; a1 = 0.0f; }
        encY[(c * 2 + 0) * 324 + r] = kan_enc(a0, -3.0f, 1.5f, 9.0f);
        encY[(c * 2 + 1) * 324 + r] = kan_enc(a1, -3.0f, 1.5f, 9.0f);
    }
    __syncthreads();

    // ---- layer2 (6 -> 12), one output pixel per thread ----
    const int ly = tid >> 4, lx = tid & 15;
    float z[12];
    #pragma unroll
    for (int c = 0; c < 6; ++c) {
        float a0 = 0.0f, a1 = 0.0f;
        int base = c * 324 + ly * 18 + lx;
        #pragma unroll
        for (int s = 0; s < 9; ++s) {
            float2 t = encY[base + (s / 3) * 18 + (s % 3)];
            float mf = floorf(t.y);
            float w  = t.y - mf;
            int  si  = (int)mf + 1;
            a0 += t.x * sbw[1][s]     + poly_eval(coefL[1][0][s][si], w);
            a1 += t.x * sbw[1][9 + s] + poly_eval(coefL[1][1][s][si], w);
        }
        z[2 * c]     = a0;
        z[2 * c + 1] = a1;
    }

    // ---- 1x1 conv (12->3) + pointwise KAN layer6 + store ----
    const int gy = ty0 + ly, gx = tx0 + lx;
    #pragma unroll
    for (int o = 0; o < 3; ++o) {
        float v = scb[o];
        #pragma unroll
        for (int c = 0; c < 12; ++c) v += scw[o * 12 + c] * z[c];
        float2 t = kan_enc(v, -2.2f, 2.5f, 11.0f);
        float mf = floorf(t.y);
        float w  = t.y - mf;
        int  si  = (int)mf + 1;
        out[((b * 3 + o) * 256 + gy) * 256 + gx] = t.x * sb6 + poly_eval(coef6[si], w);
    }
}

extern "C" void kernel_launch(void* const* d_in, const int* in_sizes, int n_in,
                              void* d_out, int out_size, void* d_ws, size_t ws_size,
                              hipStream_t stream) {
    (void)in_sizes; (void)n_in; (void)d_ws; (void)ws_size; (void)out_size;
    const float* x         = (const float*)d_in[0];
    const float* base_w1   = (const float*)d_in[1];
    const float* spline_w1 = (const float*)d_in[2];
    const float* scaler1   = (const float*)d_in[3];
    const float* base_w2   = (const float*)d_in[4];
    const float* spline_w2 = (const float*)d_in[5];
    const float* scaler2   = (const float*)d_in[6];
    const float* conv_w    = (const float*)d_in[7];
    const float* conv_b    = (const float*)d_in[8];
    const float* base_w6   = (const float*)d_in[9];
    const float* spline_w6 = (const float*)d_in[10];
    const float* scaler6   = (const float*)d_in[11];
    float* out = (float*)d_out;

    dim3 grid(256 / TILE, 256 / TILE, 4);
    dim3 block(256);
    ZS_MKAN_72121090834671_kernel<<<grid, block, 0, stream>>>(
        x, base_w1, spline_w1, scaler1, base_w2, spline_w2, scaler2,
        conv_w, conv_b, base_w6, spline_w6, scaler6, out);
}